// Round 28
// baseline (90.373 us; speedup 1.0000x reference)
//
#include <hip/hip_runtime.h>

#define LSEQ 512
#define NB 64
#define NCHUNK 51  // 16*51 = 816 >= 512 + 3*80 + 63 = 815 steps

// lanes 1..63 <- x[lane-1]; lane 0 <- old[0] (wave_shr:1, bound_ctrl=0).
// Injection MUST be fused into the old operand (lane-varying ternary around
// the DPP lets the compiler run it with exec={1..63}; exec-off SOURCE lanes
// are invalid -> lane 1 reads garbage. R12/R19/R20 all failed on this).
__device__ __forceinline__ float dpp_shr1_inj(float inj, float x) {
  return __int_as_float(__builtin_amdgcn_update_dpp(
      __float_as_int(inj), __float_as_int(x), 0x138, 0xF, 0xF, false));
}

__device__ __forceinline__ float rdlane(float x, int u) {
  return __int_as_float(__builtin_amdgcn_readlane(__float_as_int(x), u));
}

// Schraudolph exp2 for x <= 0: fmax + fma + cvt, full-rate VALU, no trans.
// Exact at x=0 (argmin weight 1.0). -INF/NaN -> 2^-126-ish junk that is
// harmless. Clamp at -126 required (args in (-383,-126) would alias to huge
// negative floats through the int conversion).
__device__ __forceinline__ float exp2_fast(float x) {
  const float xc = fmaxf(x, -126.0f);
  const float f = __builtin_fmaf(xc, 8388608.0f, 1065353216.0f);
  return __int_as_float((int)f);
}

// One 16-step chunk, 2 rows/lane, direct-form softmin (R25 cell) with the
// carried-state-INDEPENDENT arithmetic hoisted to the chunk top: diff^2 for
// both rows depends only on (p, tt[u]) — precomputed into dd0/dd1 arrays so
// the unrolled loop body contains only the dependent chain + e-path.
// (R24-R27 model: wall ~ 155cy/step fixed + 42cy/cell; in-loop recompute of
// diff^2 put 4 independent ops inside the dependent region every step.)
template <bool FULL>
__device__ __forceinline__ void chunk16(
    int cbase, const float* tgpad, const float* ringP, float* ringW, float p0,
    float p1, bool is_wr, int lane, float& v0, float& v1, float& r0) {
  // per-lane target regs + hoisted squared distances for this chunk
  float dd0[16], dd1[16];
  const int tb = 64 + cbase - lane;  // front pad 64 keeps index >= 1
#pragma unroll
  for (int k = 0; k < 16; ++k) {
    const float t = tgpad[tb + k];
    const float f0 = p0 - t;
    const float f1 = p1 - t;
    dd0[k] = f0 * f0;
    dd1[k] = f1 * f1;
  }

  // ring injection -> SGPRs: lane k (k<16) holds slot cbase+1+k
  const float rj = ringP[(cbase + 1 + (lane & 15)) & 127];
  float sj[16];
#pragma unroll
  for (int k = 0; k < 16; ++k) sj[k] = rdlane(rj, k);

  const float C23 = 1.1920929e-7f;  // 2^-23
  float vv[16];
#pragma unroll
  for (int u = 0; u < 16; ++u) {
    // R'[i0-1][j]: lanes 1..63 from lane-1's v1; lane 0 from ring SGPR
    const float r1 = dpp_shr1_inj(sj[u], v1);
    // cell0 (row i0): diag r0, up r1, left v0
    const float M0 = fminf(fminf(r0, r1), v0);
    const float md0 = __builtin_amdgcn_fmed3f(r0, r1, v0);
    const float mx0 = fmaxf(fmaxf(r0, r1), v0);
    const float e0 = (exp2_fast(M0 - md0) + exp2_fast(M0 - mx0)) + 1.0f;
    const float dm0 = dd0[u] + M0;
    const float li0 = (float)(1064992256 - __float_as_int(e0));  // KC-bits(e)
    const float d0 = __builtin_fmaf(li0, C23, dm0);
    // cell1 (row i1): diag v0_old, up d0, left v1
    const float M1 = fminf(fminf(v0, d0), v1);
    const float md1 = __builtin_amdgcn_fmed3f(v0, d0, v1);
    const float mx1 = fmaxf(fmaxf(v0, d0), v1);
    const float e1 = (exp2_fast(M1 - md1) + exp2_fast(M1 - mx1)) + 1.0f;
    const float dm1 = dd1[u] + M1;
    const float li1 = (float)(1064992256 - __float_as_int(e1));
    const float d1 = __builtin_fmaf(li1, C23, dm1);
    vv[u] = d1;
    if (FULL) {
      v0 = d0;
      v1 = d1;
    } else {
      const int j = cbase + 1 + u - lane;
      const bool act = ((unsigned)(j - 1)) < (unsigned)LSEQ;
      v0 = act ? d0 : v0;  // inactive lanes keep INF; garbage discarded
      v1 = act ? d1 : v1;
    }
    r0 = r1;
  }

  if (is_wr) {  // lane 63 publishes row 128(w+1) = its i1 (8x ds_write_b64)
    const int j0 = cbase - 62;  // even -> float2 pairs never straddle wrap
#pragma unroll
    for (int k = 0; k < 8; ++k) {
      if (FULL || (((unsigned)(j0 + 2 * k - 1)) < (unsigned)LSEQ))
        *(float2*)&ringW[(j0 + 2 * k) & 127] =
            make_float2(vv[2 * k], vv[2 * k + 1]);
      else if (((unsigned)(j0 + 2 * k)) < (unsigned)LSEQ)  // only 2nd valid
        ringW[(j0 + 2 * k + 1) & 127] = vv[2 * k + 1];
    }
  }
}

// Soft-DTW banded wavefront, one block per batch, 4 waves x 64 lanes x 2 rows.
// Lane l of wave w owns rows 128w+2l+1, +2; column j = s - 80w - l at step s.
// Ring (lag=80): entry col J read by wave w at top of chunk c was written by
// wave w-1 in its chunk c-1, burst before the top-of-c barrier; concurrent
// writes land +18..+33 past the read window (disjoint mod 128).
__global__ __launch_bounds__(256) void dtw_band(
    const float* __restrict__ pred, const float* __restrict__ target,
    float* __restrict__ part) {
  const int b = blockIdx.x;
  const int tid = threadIdx.x;  // 0..255
  const int w = tid >> 6;
  const int lane = tid & 63;
  const bool is_wr = (lane == 63) && (w < 3);

  __shared__ float tgpad[640];     // [64 pad][512 data][64 pad]
  __shared__ float rings[4][128];  // rows 0..2: interfaces; row 3: INF dummy

  const float SC = 3.79828146f;  // sqrt(C1), C1 = (1/g)*log2(e), g = 0.1
  const float2 pp = ((const float2*)(pred + b * LSEQ))[tid];
  const float p0 = pp.x * SC, p1 = pp.y * SC;  // rows 2*tid+1, 2*tid+2
  const float2 tt = ((const float2*)(target + b * LSEQ))[tid];
  ((float2*)(tgpad + 64))[tid] = make_float2(tt.x * SC, tt.y * SC);
  if (tid < 64) {
    tgpad[tid] = 0.0f;        // pads: read only by inactive cells
    tgpad[576 + tid] = 0.0f;
  }
  ((float2*)rings)[tid] = make_float2(INFINITY, INFINITY);

  const int lag = w * 80;
  const int cw0 = 5 * w;  // wave-active chunks: [cw0, cw0+35]
  const float* __restrict__ ringP = rings[w == 0 ? 3 : w - 1];
  float* __restrict__ ringW = rings[w];

  float v0 = INFINITY;                      // R'[i0][j-1]
  float v1 = INFINITY;                      // R'[i1][j-1]
  float r0 = (tid == 0) ? 0.0f : INFINITY;  // R'[i0-1][j-1]; seed R'[0][0]

  for (int c = 0; c < NCHUNK; ++c) {
    __syncthreads();  // top of chunk c (also orders init writes at c=0)
    if (c < cw0 || c > cw0 + 35) continue;  // wave-uniform
    const int cbase = 16 * c - lag;
    if (c >= cw0 + 4 && c <= cw0 + 31)
      chunk16<true>(cbase, tgpad, ringP, ringW, p0, p1, is_wr, lane, v0, v1,
                    r0);
    else
      chunk16<false>(cbase, tgpad, ringP, ringW, p0, p1, is_wr, lane, v0, v1,
                     r0);
  }

  if (tid == 255)  // row 512 = wave 3 lane 63 i1; unscale by 1/C1 = g*ln2
    part[b] = v1 * 0.069314718f;
}

__global__ void dtw_reduce(const float* __restrict__ part,
                           float* __restrict__ out) {
  float v = part[threadIdx.x];
#pragma unroll
  for (int o = 32; o > 0; o >>= 1) v += __shfl_down(v, o);
  if (threadIdx.x == 0) out[0] = v * (1.0f / NB);
}

extern "C" void kernel_launch(void* const* d_in, const int* in_sizes, int n_in,
                              void* d_out, int out_size, void* d_ws,
                              size_t ws_size, hipStream_t stream) {
  const float* pred = (const float*)d_in[0];
  const float* target = (const float*)d_in[1];
  float* part = (float*)d_ws;

  dtw_band<<<NB, 256, 0, stream>>>(pred, target, part);
  dtw_reduce<<<1, 64, 0, stream>>>(part, (float*)d_out);
}

// Round 29
// 85.191 us; speedup vs baseline: 1.0608x; 1.0608x over previous
//
#include <hip/hip_runtime.h>

#define LSEQ 512
#define NB 64
#define NCHUNK 51  // 16*51 = 816 >= 512 + 3*80 + 63 = 815 steps

// lanes 1..63 <- x[lane-1]; lane 0 <- old[0] (wave_shr:1, bound_ctrl=0).
// Injection MUST be fused into the old operand (lane-varying ternary around
// the DPP lets the compiler run it with exec={1..63}; exec-off SOURCE lanes
// are invalid -> lane 1 reads garbage. R12/R19/R20 all failed on this).
__device__ __forceinline__ float dpp_shr1_inj(float inj, float x) {
  return __int_as_float(__builtin_amdgcn_update_dpp(
      __float_as_int(inj), __float_as_int(x), 0x138, 0xF, 0xF, false));
}

__device__ __forceinline__ float rdlane(float x, int u) {
  return __int_as_float(__builtin_amdgcn_readlane(__float_as_int(x), u));
}

// Schraudolph exp2 for x <= 0: fmax + fma + cvt, full-rate VALU, no trans.
// Exact at x=0 (argmin weight = 1.0). -INF / NaN (from INF-INF) -> 2^-126.
// Clamp at -126 required: cvt saturation only protects below x ~ -383.
// Measured numerically free here (R23 absmax 0.0, R24/R25 1.0 vs thr 4.8).
__device__ __forceinline__ float exp2_fast(float x) {
  const float xc = fmaxf(x, -126.0f);
  const float f = __builtin_fmaf(xc, 8388608.0f, 1065353216.0f);
  return __int_as_float((int)f);
}
// Inverse-Schraudolph log2 for e in [1,4): (as_int(e)-1.0f_bits) * 2^-23.
__device__ __forceinline__ float log2_fast(float e) {
  return (float)(__float_as_int(e) - 1065353216) * 1.1920929e-7f;
}

// One 16-step chunk, 2 rows/lane, direct-form softmin (no (d,e) pair):
// v = d + M - log2(1 + exp2(M-med) + exp2(M-max)), all full-rate VALU.
// This is the measured family optimum (R24, 85.1us): r=2 rows/lane sits at
// the bottom of the steps x (155 + 42r) cost curve (R16/R24/R26 three-point
// fit); every scheduling/ILP/TLP/op-count variant measured within +-5% or
// worse (R13..R28). The floor is the serial dependent-VALU chain through
// two coupled cells per wavefront step — latency-structural.
template <bool FULL>
__device__ __forceinline__ void chunk16(
    int cbase, const float* tgpad, const float* ringP, float* ringW, float p0,
    float p1, bool is_wr, int lane, float& v0, float& v1, float& r0) {
  // per-lane target registers for this chunk: tt[u] = tg'[cbase+u-lane]
  float tt[16];
  const int tb = 64 + cbase - lane;  // front pad 64 keeps index >= 1
#pragma unroll
  for (int k = 0; k < 16; ++k) tt[k] = tgpad[tb + k];

  // ring injection -> SGPRs: lane k (k<16) holds slot cbase+1+k
  const float rj = ringP[(cbase + 1 + (lane & 15)) & 127];
  float sj[16];
#pragma unroll
  for (int k = 0; k < 16; ++k) sj[k] = rdlane(rj, k);

  float vv[16];
#pragma unroll
  for (int u = 0; u < 16; ++u) {
    // R'[i0-1][j]: lanes 1..63 from lane-1's v1; lane 0 from ring SGPR
    const float r1 = dpp_shr1_inj(sj[u], v1);
    const float tcu = tt[u];
    // cell0 (row i0): diag r0, up r1, left v0
    const float diff0 = p0 - tcu;
    const float M0 = fminf(fminf(r0, r1), v0);
    const float md0 = __builtin_amdgcn_fmed3f(r0, r1, v0);
    const float mx0 = fmaxf(fmaxf(r0, r1), v0);
    const float e0 =
        1.0f + (exp2_fast(M0 - md0) + exp2_fast(M0 - mx0));  // in [1,3]
    const float d0 = __builtin_fmaf(diff0, diff0, M0) - log2_fast(e0);
    // cell1 (row i1): diag v0_old, up d0, left v1
    const float diff1 = p1 - tcu;
    const float M1 = fminf(fminf(v0, d0), v1);
    const float md1 = __builtin_amdgcn_fmed3f(v0, d0, v1);
    const float mx1 = fmaxf(fmaxf(v0, d0), v1);
    const float e1 = 1.0f + (exp2_fast(M1 - md1) + exp2_fast(M1 - mx1));
    const float d1 = __builtin_fmaf(diff1, diff1, M1) - log2_fast(e1);
    vv[u] = d1;
    if (FULL) {
      v0 = d0;
      v1 = d1;
    } else {
      const int j = cbase + 1 + u - lane;
      const bool act = ((unsigned)(j - 1)) < (unsigned)LSEQ;
      v0 = act ? d0 : v0;  // inactive lanes keep INF; garbage discarded
      v1 = act ? d1 : v1;
    }
    r0 = r1;
  }

  if (is_wr) {  // lane 63 publishes row 128(w+1) = its i1 (8x ds_write_b64)
    const int j0 = cbase - 62;  // even -> float2 pairs never straddle wrap
#pragma unroll
    for (int k = 0; k < 8; ++k) {
      if (FULL || (((unsigned)(j0 + 2 * k - 1)) < (unsigned)LSEQ))
        *(float2*)&ringW[(j0 + 2 * k) & 127] =
            make_float2(vv[2 * k], vv[2 * k + 1]);
      else if (((unsigned)(j0 + 2 * k)) < (unsigned)LSEQ)  // only 2nd valid
        ringW[(j0 + 2 * k + 1) & 127] = vv[2 * k + 1];
    }
  }
}

// Soft-DTW banded wavefront, one block per batch, 4 waves x 64 lanes x 2 rows.
// Lane l of wave w owns rows 128w+2l+1, +2; column j = s - 80w - l at step s.
// Ring (lag=80): entry col J read by wave w at top of chunk c was written by
// wave w-1 in its chunk c-1, burst before the top-of-c barrier; concurrent
// writes land +18..+33 past the read window (disjoint mod 128).
__global__ __launch_bounds__(256) void dtw_band(
    const float* __restrict__ pred, const float* __restrict__ target,
    float* __restrict__ part) {
  const int b = blockIdx.x;
  const int tid = threadIdx.x;  // 0..255
  const int w = tid >> 6;
  const int lane = tid & 63;
  const bool is_wr = (lane == 63) && (w < 3);

  __shared__ float tgpad[640];     // [64 pad][512 data][64 pad]
  __shared__ float rings[4][128];  // rows 0..2: interfaces; row 3: INF dummy

  const float SC = 3.79828146f;  // sqrt(C1), C1 = (1/g)*log2(e), g = 0.1
  const float2 pp = ((const float2*)(pred + b * LSEQ))[tid];
  const float p0 = pp.x * SC, p1 = pp.y * SC;  // rows 2*tid+1, 2*tid+2
  const float2 tt = ((const float2*)(target + b * LSEQ))[tid];
  ((float2*)(tgpad + 64))[tid] = make_float2(tt.x * SC, tt.y * SC);
  if (tid < 64) {
    tgpad[tid] = 0.0f;        // pads: read only by inactive cells
    tgpad[576 + tid] = 0.0f;
  }
  ((float2*)rings)[tid] = make_float2(INFINITY, INFINITY);

  const int lag = w * 80;
  const int cw0 = 5 * w;  // wave-active chunks: [cw0, cw0+35]
  const float* __restrict__ ringP = rings[w == 0 ? 3 : w - 1];
  float* __restrict__ ringW = rings[w];

  float v0 = INFINITY;                      // R'[i0][j-1]
  float v1 = INFINITY;                      // R'[i1][j-1]
  float r0 = (tid == 0) ? 0.0f : INFINITY;  // R'[i0-1][j-1]; seed R'[0][0]

  for (int c = 0; c < NCHUNK; ++c) {
    __syncthreads();  // top of chunk c (also orders init writes at c=0)
    if (c < cw0 || c > cw0 + 35) continue;  // wave-uniform
    const int cbase = 16 * c - lag;
    if (c >= cw0 + 4 && c <= cw0 + 31)
      chunk16<true>(cbase, tgpad, ringP, ringW, p0, p1, is_wr, lane, v0, v1,
                    r0);
    else
      chunk16<false>(cbase, tgpad, ringP, ringW, p0, p1, is_wr, lane, v0, v1,
                     r0);
  }

  if (tid == 255)  // row 512 = wave 3 lane 63 i1; unscale by 1/C1 = g*ln2
    part[b] = v1 * 0.069314718f;
}

__global__ void dtw_reduce(const float* __restrict__ part,
                           float* __restrict__ out) {
  float v = part[threadIdx.x];
#pragma unroll
  for (int o = 32; o > 0; o >>= 1) v += __shfl_down(v, o);
  if (threadIdx.x == 0) out[0] = v * (1.0f / NB);
}

extern "C" void kernel_launch(void* const* d_in, const int* in_sizes, int n_in,
                              void* d_out, int out_size, void* d_ws,
                              size_t ws_size, hipStream_t stream) {
  const float* pred = (const float*)d_in[0];
  const float* target = (const float*)d_in[1];
  float* part = (float*)d_ws;

  dtw_band<<<NB, 256, 0, stream>>>(pred, target, part);
  dtw_reduce<<<1, 64, 0, stream>>>(part, (float*)d_out);
}